// Round 9
// baseline (550.728 us; speedup 1.0000x reference)
//
#include <hip/hip_runtime.h>
#include <math.h>

#define DIN  512
#define DOUT 512
#define CHK  64
#define NCH  64
#define NB   8
#define SEQ  4096

typedef short bh8_t __attribute__((ext_vector_type(8)));
typedef float f32x4 __attribute__((ext_vector_type(4)));

__device__ __forceinline__ float sigmoidf_(float z){ return 1.0f/(1.0f+__expf(-z)); }

__device__ __forceinline__ unsigned short f2bf(float f){
  unsigned u = __float_as_uint(f);
  unsigned r = (u + 0x7fffu + ((u>>16)&1u)) >> 16;
  return (unsigned short)r;
}
__device__ __forceinline__ void store_bf4(unsigned short* p, float4 v){
  uint2 u;
  u.x = (unsigned)f2bf(v.x) | ((unsigned)f2bf(v.y)<<16);
  u.y = (unsigned)f2bf(v.z) | ((unsigned)f2bf(v.w)<<16);
  *(uint2*)p = u;
}

// ---------------- K0: M0 -> bf16 ----------------
__global__ __launch_bounds__(256) void k0_m0h(const float* __restrict__ M0, unsigned short* __restrict__ M0h){
  int idx = (blockIdx.x*256 + threadIdx.x)*4;
  float4 v = *(const float4*)(M0+idx);
  store_bf4(M0h+idx, v);
}

// ---------------- K1: per-(batch,chunk) statistics (+ x -> bf16) ----------------
__global__ __launch_bounds__(256) void k1_stats(
    const float* __restrict__ x,
    const float* __restrict__ eta_w, const float* __restrict__ eta_b,
    const float* __restrict__ alpha_w, const float* __restrict__ alpha_b,
    const float* __restrict__ gate_w, const float* __restrict__ gate_b,
    float* __restrict__ KM, float* __restrict__ Dv, unsigned short* __restrict__ KMh,
    float* __restrict__ C1, float* __restrict__ C2, float* __restrict__ KM2, float* __restrict__ Q,
    unsigned short* __restrict__ xh)
{
  int j = blockIdx.x, b = blockIdx.y;
  const float* xc = x + ((size_t)b*SEQ + (size_t)j*CHK) * DIN;
  int tid = threadIdx.x;
  int wave = tid >> 6, lane = tid & 63;

  float km_acc[8], xb_acc[8];
#pragma unroll
  for (int k=0;k<8;k++){ km_acc[k]=0.f; xb_acc[k]=0.f; }
  float eta_sum = 0.f, alpha_sum = 0.f;
  float ew[8], aw[8];
#pragma unroll
  for (int k=0;k<8;k++){ ew[k]=eta_w[lane*8+k]; aw[k]=alpha_w[lane*8+k]; }

  for (int tt=0; tt<16; tt++){
    int t = wave*16 + tt;
    const float* xr = xc + (size_t)t*DIN + lane*8;
    float v[8];
#pragma unroll
    for (int k=0;k<8;k++) v[k]=xr[k];
    if (xh){
      uint4 hv;
      hv.x = (unsigned)f2bf(v[0]) | ((unsigned)f2bf(v[1])<<16);
      hv.y = (unsigned)f2bf(v[2]) | ((unsigned)f2bf(v[3])<<16);
      hv.z = (unsigned)f2bf(v[4]) | ((unsigned)f2bf(v[5])<<16);
      hv.w = (unsigned)f2bf(v[6]) | ((unsigned)f2bf(v[7])<<16);
      *(uint4*)&xh[((size_t)b*SEQ + (size_t)j*CHK + t)*DIN + lane*8] = hv;
    }
    float pe=0.f, pa=0.f, pn=0.f;
#pragma unroll
    for (int k=0;k<8;k++){ pe += v[k]*ew[k]; pa += v[k]*aw[k]; pn += v[k]*v[k]; }
#pragma unroll
    for (int off=32; off; off>>=1){
      pe += __shfl_xor(pe, off);
      pa += __shfl_xor(pa, off);
      pn += __shfl_xor(pn, off);
    }
    float inv = 1.0f / fmaxf(sqrtf(pn), 1e-5f);
    eta_sum   += sigmoidf_(pe + eta_b[0]);
    alpha_sum += sigmoidf_(pa + alpha_b[0]);
#pragma unroll
    for (int k=0;k<8;k++){ km_acc[k] += v[k]*inv; xb_acc[k] += v[k]; }
  }

  __shared__ float sKM[4][DIN];
  __shared__ float sXB[4][DIN];
  __shared__ float sEA[4][2];
  __shared__ float sred[4][2];
#pragma unroll
  for (int k=0;k<8;k++){ sKM[wave][lane*8+k]=km_acc[k]; sXB[wave][lane*8+k]=xb_acc[k]; }
  if (lane==0){ sEA[wave][0]=eta_sum; sEA[wave][1]=alpha_sum; }
  __syncthreads();

  float gpart=0.f, km2part=0.f;
  float kmv[2], dvv[2];
#pragma unroll
  for (int k=0;k<2;k++){
    int d = tid*2+k;
    float km = (sKM[0][d]+sKM[1][d]+sKM[2][d]+sKM[3][d]) * (1.0f/64.0f);
    float xb = (sXB[0][d]+sXB[1][d]+sXB[2][d]+sXB[3][d]) * (1.0f/64.0f);
    kmv[k]=km; dvv[k]=xb-km;
    gpart  += km * gate_w[d];
    km2part+= km * km;
  }
#pragma unroll
  for (int off=32; off; off>>=1){
    gpart   += __shfl_xor(gpart, off);
    km2part += __shfl_xor(km2part, off);
  }
  if (lane==0){ sred[wave][0]=gpart; sred[wave][1]=km2part; }
  __syncthreads();

  size_t base = ((size_t)b*NCH + j)*DIN;
#pragma unroll
  for (int k=0;k<2;k++){
    int d = tid*2+k;
    KM[base+d]=kmv[k];
    Dv[base+d]=dvv[k];
    KMh[base+d]=f2bf(kmv[k]);
  }
  if (tid==0){
    float gdot = sred[0][0]+sred[1][0]+sred[2][0]+sred[3][0];
    float km2  = sred[0][1]+sred[1][1]+sred[2][1]+sred[3][1];
    float etam = (sEA[0][0]+sEA[1][0]+sEA[2][0]+sEA[3][0]) * (1.0f/64.0f);
    float alpm = (sEA[0][1]+sEA[1][1]+sEA[2][1]+sEA[3][1]) * (1.0f/64.0f);
    float eta   = 0.2f * etam;
    float alpha = 0.5f + 0.5f * alpm;
    float gate  = sigmoidf_(gdot + gate_b[0]);
    float c1 = gate*alpha + 1.0f - gate;
    float c2 = gate*eta;
    C1[b*NCH+j]  = c1;
    C2[b*NCH+j]  = c2;
    KM2[b*NCH+j] = km2;
    Q[b*NCH+j]   = c2/c1;
  }
}

// ---------------- K2: G0 = D @ M0^T, H0 = KM @ M0^T (o split in halves) ----------------
__global__ __launch_bounds__(256) void k2_g0h0(
    const float* __restrict__ KM, const float* __restrict__ Dv,
    const float* __restrict__ M0, float* __restrict__ G0, float* __restrict__ H0)
{
  int j = blockIdx.x, b = blockIdx.y, half = blockIdx.z;
  __shared__ float sD[DIN], sK[DIN];
  int tid = threadIdx.x;
  size_t base = ((size_t)b*NCH+j)*DIN;
  for (int d=tid; d<DIN; d+=256){ sD[d]=Dv[base+d]; sK[d]=KM[base+d]; }
  __syncthreads();
  int o = half*256 + tid;
  const float* mr = M0 + (size_t)o*DIN;
  float ag=0.f, ah=0.f;
  for (int d=0; d<DIN; d+=4){
    float4 m = *(const float4*)(mr+d);
    ag += m.x*sD[d] + m.y*sD[d+1] + m.z*sD[d+2] + m.w*sD[d+3];
    ah += m.x*sK[d] + m.y*sK[d+1] + m.z*sK[d+2] + m.w*sK[d+3];
  }
  G0[base+o]=ag; H0[base+o]=ah;
}

// ---------------- K2b: Gram matrices, transposed + q-scaled output ----------------
// GT[b][j][i] = q_i * (km_i . d_j), WT[b][j][i] = q_i * (km_i . km_j)
__global__ __launch_bounds__(512) void k2b_gram(
    const float* __restrict__ KM, const float* __restrict__ Dv,
    const float* __restrict__ Q,
    float* __restrict__ GT, float* __restrict__ WT)
{
  int i = blockIdx.x, b = blockIdx.y;
  __shared__ float sKi[DIN];
  int tid = threadIdx.x;
  const float* kmi = KM + ((size_t)b*NCH+i)*DIN;
  for (int d=tid; d<DIN; d+=512) sKi[d]=kmi[d];
  __syncthreads();
  float qi = Q[b*NCH+i];
  int wave = tid>>6, lane = tid&63;
  for (int j=wave; j<NCH; j+=8){
    const float* dj = Dv + ((size_t)b*NCH+j)*DIN;
    const float* kj = KM + ((size_t)b*NCH+j)*DIN;
    float pd=0.f, pk=0.f;
#pragma unroll
    for (int k=0;k<8;k++){
      int d = lane + k*64;
      pd += sKi[d]*dj[d];
      pk += sKi[d]*kj[d];
    }
#pragma unroll
    for (int off=32; off; off>>=1){ pd += __shfl_xor(pd,off); pk += __shfl_xor(pk,off); }
    if (lane==0){
      GT[((size_t)b*NCH+j)*NCH + i] = qi*pd;
      WT[((size_t)b*NCH+j)*NCH + i] = qi*pk;
    }
  }
}

// ---------------- K3a: d-sliced triangular recurrence + dots + UQT pack ----------------
// grid (8, NB), 64 threads (1 wave). Block owns d = dblk*64 + lane.
__global__ __launch_bounds__(64) void k3a_rec(
    const float* __restrict__ G0, const float* __restrict__ H0,
    const float* __restrict__ GT, const float* __restrict__ WT,
    const float* __restrict__ Q,
    float* __restrict__ AU, unsigned short* __restrict__ UQTh, float* __restrict__ DOTS)
{
  int dblk = blockIdx.x, b = blockIdx.y;
  int lane = threadIdx.x;
  int d = dblk*64 + lane;

  __shared__ float sMT[NCH*NCH];
  __shared__ float sWT[NCH*NCH];
  __shared__ float sq[NCH];

  // stage transposed scaled Grams with strict-lower-triangular mask (keep i<j)
  const float4* gt4 = (const float4*)&GT[(size_t)b*NCH*NCH];
  const float4* wt4 = (const float4*)&WT[(size_t)b*NCH*NCH];
#pragma unroll
  for (int t=0;t<16;t++){
    int idx4 = t*64 + lane;       // float4 index
    int idx  = idx4*4;
    int j = idx>>6, i0 = idx&63;
    float4 g = gt4[idx4];
    float4 w = wt4[idx4];
    if (i0+0 >= j){ g.x=0.f; w.x=0.f; }
    if (i0+1 >= j){ g.y=0.f; w.y=0.f; }
    if (i0+2 >= j){ g.z=0.f; w.z=0.f; }
    if (i0+3 >= j){ g.w=0.f; w.w=0.f; }
    *(float4*)&sMT[idx] = g;
    *(float4*)&sWT[idx] = w;
  }
  sq[lane] = Q[b*NCH+lane];
  __syncthreads();

  // preload G0 column slice
  float au[NCH];
  size_t gb = (size_t)b*NCH*DOUT + d;
#pragma unroll
  for (int j=0;j<NCH;j++) au[j] = G0[gb + (size_t)j*DOUT];

  // phase 1: triangular recurrence, b128 row reads (zero-padded tail groups)
#pragma unroll
  for (int j=1;j<NCH;j++){
    float a = au[j];
    const f32x4* row = (const f32x4*)&sMT[j*64];
    int ng = (j+3)>>2;
#pragma unroll
    for (int g=0; g<ng; g++){
      f32x4 c = row[g];
      a += c[0]*au[g*4+0] + c[1]*au[g*4+1] + c[2]*au[g*4+2] + c[3]*au[g*4+3];
    }
    au[j] = a;
  }
#pragma unroll
  for (int j=0;j<NCH;j++) AU[gb + (size_t)j*DOUT] = au[j];

  // UQT pack: row d, 64 bf16 (q_i * au_i)
#pragma unroll
  for (int g=0; g<8; g++){
    uint4 hv;
    hv.x = (unsigned)f2bf(au[g*8+0]*sq[g*8+0]) | ((unsigned)f2bf(au[g*8+1]*sq[g*8+1])<<16);
    hv.y = (unsigned)f2bf(au[g*8+2]*sq[g*8+2]) | ((unsigned)f2bf(au[g*8+3]*sq[g*8+3])<<16);
    hv.z = (unsigned)f2bf(au[g*8+4]*sq[g*8+4]) | ((unsigned)f2bf(au[g*8+5]*sq[g*8+5])<<16);
    hv.w = (unsigned)f2bf(au[g*8+6]*sq[g*8+6]) | ((unsigned)f2bf(au[g*8+7]*sq[g*8+7])<<16);
    *(uint4*)&UQTh[((size_t)b*DOUT + d)*NCH + g*8] = hv;
  }

  // phase 2: w_j and dot partials for this d-slice
#pragma unroll
  for (int j=0;j<NCH;j++){
    float w = H0[gb + (size_t)j*DOUT];
    const f32x4* row = (const f32x4*)&sWT[j*64];
    int ng = (j+3)>>2;
#pragma unroll
    for (int g=0; g<ng; g++){
      f32x4 c = row[g];
      w += c[0]*au[g*4+0] + c[1]*au[g*4+1] + c[2]*au[g*4+2] + c[3]*au[g*4+3];
    }
    float s1 = au[j]*w, s2 = au[j]*au[j];
#pragma unroll
    for (int off=32; off; off>>=1){ s1+=__shfl_xor(s1,off); s2+=__shfl_xor(s2,off); }
    if (lane==0){
      DOTS[(((size_t)b*8+dblk)*NCH+j)*2+0] = s1;
      DOTS[(((size_t)b*8+dblk)*NCH+j)*2+1] = s2;
    }
  }
}

// ---------------- K3b: F0 + combine dot partials + serial p-chain ----------------
__global__ __launch_bounds__(256) void k3b_chain(
    const float* __restrict__ M0, const float* __restrict__ DOTS,
    const float* __restrict__ C1, const float* __restrict__ C2, const float* __restrict__ KM2,
    float* __restrict__ P)
{
  int b = blockIdx.x;
  int tid = threadIdx.x, wave = tid>>6, lane = tid&63;
  __shared__ float sF[4];
  __shared__ float suw[NCH], suu[NCH], sc1[NCH], sc2[NCH], skm2[NCH];

  float f0p = 0.f;
  const float4* m4 = (const float4*)M0;
  for (int i=tid; i<(DOUT*DIN)/4; i+=256){
    float4 v = m4[i];
    f0p += v.x*v.x + v.y*v.y + v.z*v.z + v.w*v.w;
  }
#pragma unroll
  for (int off=32; off; off>>=1) f0p += __shfl_xor(f0p, off);
  if (lane==0) sF[wave]=f0p;

  if (tid < NCH){
    float uw=0.f, uu=0.f;
#pragma unroll
    for (int k=0;k<8;k++){
      uw += DOTS[(((size_t)b*8+k)*NCH+tid)*2+0];
      uu += DOTS[(((size_t)b*8+k)*NCH+tid)*2+1];
    }
    suw[tid]=uw; suu[tid]=uu;
    sc1[tid]=C1[b*NCH+tid]; sc2[tid]=C2[b*NCH+tid]; skm2[tid]=KM2[b*NCH+tid];
  }
  __syncthreads();

  if (tid==0){
    float F = sF[0]+sF[1]+sF[2]+sF[3];
    float p = 1.f;
    P[b*65+0] = 1.f;
    for (int j=0;j<NCH;j++){
      float uw = suw[j], uu = suu[j];
      float c1 = sc1[j], c2 = sc2[j], km2 = skm2[j];
      uw *= p*p; uu *= p*p;
      float Fnew = c1*c1*F + 2.f*c1*c2*uw + c2*c2*uu*km2;
      float scale = fminf(30.0f/(sqrtf(Fnew)+1e-6f), 1.0f);
      F = scale*scale*Fnew;
      p = scale*c1*p;
      P[b*65+j+1] = p;
    }
  }
}

// ---------------- K4: fused out tile 256x128 + in-block S, 8 waves (4x2), XCD-local ----------------
// Computes S = X_tile @ KMh^T in the same K-loop as the main GEMM (shared As),
// then applies the causal-masked correction S @ UQT^T. Replaces k4s_s entirely.
#define ASTRIDE 80
__global__ __launch_bounds__(512, 4) void k4_out(
    const float* __restrict__ x, const unsigned short* __restrict__ xh,
    const unsigned short* __restrict__ M0h, const unsigned short* __restrict__ KMh,
    const unsigned short* __restrict__ UQTh,
    const float* __restrict__ P, float* __restrict__ out, int use_xh)
{
  // XCD-locality swizzle: each XCD owns one batch b (4MB xh fits its L2).
  int n = blockIdx.x;                 // 0..511
  int xcd = n & 7, local = n >> 3;
  int work = xcd*64 + local;          // bijective
  int ot = work & 3, rb = (work>>2) & 15, b = work >> 6;   // b == xcd

  int tid = threadIdx.x;
  int lane = tid&63, w = tid>>6, m = lane&15, q = lane>>4;
  int wr = w>>1, wc = w&1;
  int O0 = ot*128;
  int R0 = rb*256;

  // pool: As 256xASTRIDE shorts (40960B) + Bs 192xASTRIDE (30720B) = 71680B
  // Bs rows 0..127: M0h O-slice; rows 128..191: KMh (all 64 rows)
  // epilogue reuses pool: per-wave 16x68 floats x 8 = 34816B
  __shared__ __align__(16) char pool[(256+192)*ASTRIDE*2];
  unsigned short* As = (unsigned short*)pool;
  unsigned short* Bs = (unsigned short*)pool + 256*ASTRIDE;
  float* ep = (float*)pool;

  f32x4 acc[4][4];     // main: X @ M0h^T
  f32x4 accS[4][2];    // S: X @ KMh^T (wave covers 64 rows x 32 S-cols)
  f32x4 z = {0.f,0.f,0.f,0.f};
#pragma unroll
  for (int mi=0;mi<4;mi++){
#pragma unroll
    for (int nf=0;nf<4;nf++) acc[mi][nf]=z;
#pragma unroll
    for (int sf=0;sf<2;sf++) accS[mi][sf]=z;
  }

  // prefetch k0=0 tiles into registers
  uint4 pBM[2], pBK, pA[4];
  float4 xa[8];
#pragma unroll
  for (int v=0;v<2;v++){
    int idx=v*512+tid; int ol=idx>>3, cc=idx&7;
    pBM[v] = *(const uint4*)&M0h[(size_t)(O0+ol)*DIN + 0 + cc*8];
  }
  {
    int il = tid>>3, cc = tid&7;
    pBK = *(const uint4*)&KMh[((size_t)b*NCH+il)*DIN + 0 + cc*8];
  }
  if (use_xh){
#pragma unroll
    for (int v=0;v<4;v++){
      int idx=v*512+tid; int row=idx>>3, cc=idx&7;
      pA[v] = *(const uint4*)&xh[((size_t)b*SEQ + R0 + row)*DIN + 0 + cc*8];
    }
  } else {
#pragma unroll
    for (int v=0;v<8;v++){
      int idx=v*512+tid; int row=idx>>4, cc=idx&15;
      xa[v] = *(const float4*)(x + ((size_t)b*SEQ + R0 + row)*DIN + 0 + cc*4);
    }
  }

  // ---- main K loop: acc += X @ M0h^T ; accS += X @ KMh^T ----
  for (int k0=0;k0<DIN;k0+=64){
    __syncthreads();                 // previous MFMA done reading As/Bs
#pragma unroll
    for (int v=0;v<2;v++){
      int idx=v*512+tid; int ol=idx>>3, cc=idx&7;
      *(uint4*)&Bs[ol*ASTRIDE + cc*8] = pBM[v];
    }
    {
      int il = tid>>3, cc = tid&7;
      *(uint4*)&Bs[(128+il)*ASTRIDE + cc*8] = pBK;
    }
    if (use_xh){
#pragma unroll
      for (int v=0;v<4;v++){
        int idx=v*512+tid; int row=idx>>3, cc=idx&7;
        *(uint4*)&As[row*ASTRIDE + cc*8] = pA[v];
      }
    } else {
#pragma unroll
      for (int v=0;v<8;v++){
        int idx=v*512+tid; int row=idx>>4, cc=idx&15;
        store_bf4(&As[row*ASTRIDE + cc*4], xa[v]);
      }
    }
    // prefetch next k-tile (latency hides under MFMA below)
    int kn = k0 + 64;
    if (kn < DIN){
#pragma unroll
      for (int v=0;v<2;v++){
        int idx=v*512+tid; int ol=idx>>3, cc=idx&7;
        pBM[v] = *(const uint4*)&M0h[(size_t)(O0+ol)*DIN + kn + cc*8];
      }
      {
        int il = tid>>3, cc = tid&7;
        pBK = *(const uint4*)&KMh[((size_t)b*NCH+il)*DIN + kn + cc*8];
      }
      if (use_xh){
#pragma unroll
        for (int v=0;v<4;v++){
          int idx=v*512+tid; int row=idx>>3, cc=idx&7;
          pA[v] = *(const uint4*)&xh[((size_t)b*SEQ + R0 + row)*DIN + kn + cc*8];
        }
      } else {
#pragma unroll
        for (int v=0;v<8;v++){
          int idx=v*512+tid; int row=idx>>4, cc=idx&15;
          xa[v] = *(const float4*)(x + ((size_t)b*SEQ + R0 + row)*DIN + kn + cc*4);
        }
      }
    }
    __syncthreads();
#pragma unroll
    for (int kk=0;kk<2;kk++){
#pragma unroll
      for (int mi=0;mi<4;mi++){
        bh8_t af = *(bh8_t*)&As[(wr*64+mi*16+m)*ASTRIDE + kk*32 + q*8];
#pragma unroll
        for (int nf=0;nf<4;nf++){
          bh8_t bf_ = *(bh8_t*)&Bs[(wc*64+nf*16+m)*ASTRIDE + kk*32 + q*8];
          acc[mi][nf] = __builtin_amdgcn_mfma_f32_16x16x32_bf16(af, bf_, acc[mi][nf], 0,0,0);
        }
#pragma unroll
        for (int sf=0;sf<2;sf++){
          bh8_t bs_ = *(bh8_t*)&Bs[(128+wc*32+sf*16+m)*ASTRIDE + kk*32 + q*8];
          accS[mi][sf] = __builtin_amdgcn_mfma_f32_16x16x32_bf16(af, bs_, accS[mi][sf], 0,0,0);
        }
      }
    }
  }

  // ---- correction setup: masked bf16 S -> As, UQT slice -> Bs ----
  __syncthreads();                    // all K-loop MFMAs done
#pragma unroll
  for (int v=0; v<2; v++){
    int idx = v*512 + tid;            // 128 rows x 8 granules
    int ol = idx>>3, cc = idx&7;
    *(uint4*)&Bs[ol*ASTRIDE + cc*8] = *(const uint4*)&UQTh[((size_t)b*DOUT + O0+ol)*NCH + cc*8];
  }
  // S fragment: row_local = mi*16 + q*4 + r (within wave's 64 rows), col i = wc*32 + sf*16 + m
#pragma unroll
  for (int mi=0;mi<4;mi++){
#pragma unroll
    for (int sf=0;sf<2;sf++){
      int i = wc*32 + sf*16 + m;
#pragma unroll
      for (int r=0;r<4;r++){
        int rloc = wr*64 + mi*16 + q*4 + r;
        int j = (R0 + rloc)>>6;       // chunk of this x-row
        unsigned short hv = (i < j) ? f2bf(accS[mi][sf][r]) : (unsigned short)0;
        As[rloc*ASTRIDE + i] = hv;
      }
    }
  }
  __syncthreads();
  // correction MFMA: acc += S_masked @ UQT^T
#pragma unroll
  for (int kk=0;kk<2;kk++){
#pragma unroll
    for (int mi=0;mi<4;mi++){
      bh8_t af = *(bh8_t*)&As[(wr*64+mi*16+m)*ASTRIDE + kk*32 + q*8];
#pragma unroll
      for (int nf=0;nf<4;nf++){
        bh8_t bf_ = *(bh8_t*)&Bs[(wc*64+nf*16+m)*ASTRIDE + kk*32 + q*8];
        acc[mi][nf] = __builtin_amdgcn_mfma_f32_16x16x32_bf16(af, bf_, acc[mi][nf], 0,0,0);
      }
    }
  }

  // ---- epilogue: per-wave transpose, p-scale, nontemporal coalesced stores ----
  __syncthreads();                       // all MFMAs done before pool reuse
  float p = P[b*65 + rb*4 + wr];         // wave's 64 rows all in chunk rb*4+wr
  float* epw = ep + w*(16*68);
#pragma unroll
  for (int mi=0; mi<4; mi++){
#pragma unroll
    for (int nf=0;nf<4;nf++)
#pragma unroll
      for (int r=0;r<4;r++)
        epw[(q*4+r)*68 + nf*16 + m] = p*acc[mi][nf][r];
    // per-wave scratch: in-order LDS within wave, no cross-wave barrier needed
#pragma unroll
    for (int v=0;v<4;v++){
      int idx = v*64 + lane;
      int row = idx>>4, c4 = idx&15;
      f32x4 vv = *(f32x4*)&epw[row*68 + c4*4];
      f32x4* pdst = (f32x4*)&out[((size_t)b*SEQ + R0 + wr*64 + mi*16 + row)*DOUT + O0 + wc*64 + c4*4];
      __builtin_nontemporal_store(vv, pdst);
    }
  }
}

// ---------------- K5: M_fin = p64*(M0 + sum_i q_i AU_i km_i^T) ----------------
__global__ __launch_bounds__(256) void k5_mfin(
    const float* __restrict__ M0, const float* __restrict__ KM,
    const float* __restrict__ AU, const float* __restrict__ P, const float* __restrict__ Q,
    float* __restrict__ Mout)
{
  int ob = blockIdx.x, b = blockIdx.y;
  int tid = threadIdx.x;
  __shared__ float uo[64][8];
  for (int idx=tid; idx<512; idx+=256){
    int i = idx>>3, oo = idx&7;
    uo[i][oo] = Q[b*NCH+i] * AU[((size_t)b*NCH+i)*DOUT + ob*8+oo];
  }
  __syncthreads();
  float p64 = P[b*65+NCH];
  float acc[2][8];
#pragma unroll
  for (int h=0;h<2;h++)
#pragma unroll
    for (int oo=0;oo<8;oo++) acc[h][oo]=0.f;
  int d0 = tid, d1 = tid+256;
  for (int i=0;i<64;i++){
    float k0 = KM[((size_t)b*NCH+i)*DIN + d0];
    float k1 = KM[((size_t)b*NCH+i)*DIN + d1];
#pragma unroll
    for (int oo=0;oo<8;oo++){
      float u = uo[i][oo];
      acc[0][oo] += u*k0;
      acc[1][oo] += u*k1;
    }
  }
#pragma unroll
  for (int oo=0;oo<8;oo++){
    int o = ob*8+oo;
    Mout[((size_t)b*DOUT + o)*DIN + d0] = p64*(M0[(size_t)o*DIN+d0] + acc[0][oo]);
    Mout[((size_t)b*DOUT + o)*DIN + d1] = p64*(M0[(size_t)o*DIN+d1] + acc[1][oo]);
  }
}

// ---------------- launch ----------------
extern "C" void kernel_launch(void* const* d_in, const int* in_sizes, int n_in,
                              void* d_out, int out_size, void* d_ws, size_t ws_size,
                              hipStream_t stream) {
  const float* x       = (const float*)d_in[0];
  const float* M0      = (const float*)d_in[1];
  const float* eta_w   = (const float*)d_in[2];
  const float* eta_b   = (const float*)d_in[3];
  const float* alpha_w = (const float*)d_in[4];
  const float* alpha_b = (const float*)d_in[5];
  const float* gate_w  = (const float*)d_in[6];
  const float* gate_b  = (const float*)d_in[7];
  float* out = (float*)d_out;

  float* ws = (float*)d_ws;
  // fp32 region
  float* KM   = ws;                    // 262144
  float* Dv   = KM   + 262144;
  float* G0   = Dv   + 262144;
  float* H0   = G0   + 262144;
  float* AU   = H0   + 262144;
  float* GT   = AU   + 262144;         // 32768 (transposed q-scaled KMD)
  float* WT   = GT   + 32768;          // 32768 (transposed q-scaled KMKM)
  float* C1   = WT   + 32768;          // 512
  float* C2   = C1   + 512;
  float* KM2  = C2   + 512;
  float* Q    = KM2  + 512;
  float* P    = Q    + 512;            // 1024 (8*65 used)
  float* DOTS = P    + 1024;           // 8192 (NB*8*64*2)
  // bf16 region
  unsigned short* M0h  = (unsigned short*)(DOTS + 8192);   // 262144 shorts
  unsigned short* KMh  = M0h  + 262144;                    // 262144
  unsigned short* Sh   = KMh  + 262144;                    // 2097152 (unused; kept for layout)
  unsigned short* UQTh = Sh   + 2097152;                   // 262144
  unsigned short* xh   = UQTh + 262144;                    // 16777216 (optional)

  size_t base_bytes = (size_t)((char*)xh - (char*)d_ws);
  size_t need_xh = base_bytes + (size_t)16777216*2;
  int use_xh = (ws_size >= need_xh) ? 1 : 0;
  unsigned short* xh_arg = use_xh ? xh : (unsigned short*)0;

  k0_m0h<<<dim3(256), 256, 0, stream>>>(M0, M0h);
  k1_stats<<<dim3(NCH, NB), 256, 0, stream>>>(x, eta_w, eta_b, alpha_w, alpha_b,
                                              gate_w, gate_b, KM, Dv, KMh, C1, C2, KM2, Q, xh_arg);
  k2_g0h0<<<dim3(NCH, NB, 2), 256, 0, stream>>>(KM, Dv, M0, G0, H0);
  k2b_gram<<<dim3(NCH, NB), 512, 0, stream>>>(KM, Dv, Q, GT, WT);
  k3a_rec<<<dim3(8, NB), 64, 0, stream>>>(G0, H0, GT, WT, Q, AU, UQTh, DOTS);
  k3b_chain<<<dim3(NB), 256, 0, stream>>>(M0, DOTS, C1, C2, KM2, P);
  k4_out<<<dim3(512), 512, 0, stream>>>(x, xh, M0h, KMh, UQTh, P, out, use_xh);
  k5_mfin<<<dim3(64, NB), 256, 0, stream>>>(M0, KM, AU, P, Q, out + (size_t)NB*SEQ*DOUT);
}

// Round 10
// 513.309 us; speedup vs baseline: 1.0729x; 1.0729x over previous
//
#include <hip/hip_runtime.h>
#include <math.h>

#define DIN  512
#define DOUT 512
#define CHK  64
#define NCH  64
#define NB   8
#define SEQ  4096

typedef short bh8_t __attribute__((ext_vector_type(8)));
typedef float f32x4 __attribute__((ext_vector_type(4)));

__device__ __forceinline__ float sigmoidf_(float z){ return 1.0f/(1.0f+__expf(-z)); }

__device__ __forceinline__ unsigned short f2bf(float f){
  unsigned u = __float_as_uint(f);
  unsigned r = (u + 0x7fffu + ((u>>16)&1u)) >> 16;
  return (unsigned short)r;
}
__device__ __forceinline__ void store_bf4(unsigned short* p, float4 v){
  uint2 u;
  u.x = (unsigned)f2bf(v.x) | ((unsigned)f2bf(v.y)<<16);
  u.y = (unsigned)f2bf(v.z) | ((unsigned)f2bf(v.w)<<16);
  *(uint2*)p = u;
}

// ---------------- K0: M0 -> bf16 ----------------
__global__ __launch_bounds__(256) void k0_m0h(const float* __restrict__ M0, unsigned short* __restrict__ M0h){
  int idx = (blockIdx.x*256 + threadIdx.x)*4;
  float4 v = *(const float4*)(M0+idx);
  store_bf4(M0h+idx, v);
}

// ---------------- K1: per-(batch,chunk) statistics (+ x -> bf16) ----------------
__global__ __launch_bounds__(256) void k1_stats(
    const float* __restrict__ x,
    const float* __restrict__ eta_w, const float* __restrict__ eta_b,
    const float* __restrict__ alpha_w, const float* __restrict__ alpha_b,
    const float* __restrict__ gate_w, const float* __restrict__ gate_b,
    float* __restrict__ KM, float* __restrict__ Dv, unsigned short* __restrict__ KMh,
    float* __restrict__ C1, float* __restrict__ C2, float* __restrict__ KM2, float* __restrict__ Q,
    unsigned short* __restrict__ xh)
{
  int j = blockIdx.x, b = blockIdx.y;
  const float* xc = x + ((size_t)b*SEQ + (size_t)j*CHK) * DIN;
  int tid = threadIdx.x;
  int wave = tid >> 6, lane = tid & 63;

  float km_acc[8], xb_acc[8];
#pragma unroll
  for (int k=0;k<8;k++){ km_acc[k]=0.f; xb_acc[k]=0.f; }
  float eta_sum = 0.f, alpha_sum = 0.f;
  float ew[8], aw[8];
#pragma unroll
  for (int k=0;k<8;k++){ ew[k]=eta_w[lane*8+k]; aw[k]=alpha_w[lane*8+k]; }

  for (int tt=0; tt<16; tt++){
    int t = wave*16 + tt;
    const float* xr = xc + (size_t)t*DIN + lane*8;
    float v[8];
#pragma unroll
    for (int k=0;k<8;k++) v[k]=xr[k];
    if (xh){
      uint4 hv;
      hv.x = (unsigned)f2bf(v[0]) | ((unsigned)f2bf(v[1])<<16);
      hv.y = (unsigned)f2bf(v[2]) | ((unsigned)f2bf(v[3])<<16);
      hv.z = (unsigned)f2bf(v[4]) | ((unsigned)f2bf(v[5])<<16);
      hv.w = (unsigned)f2bf(v[6]) | ((unsigned)f2bf(v[7])<<16);
      *(uint4*)&xh[((size_t)b*SEQ + (size_t)j*CHK + t)*DIN + lane*8] = hv;
    }
    float pe=0.f, pa=0.f, pn=0.f;
#pragma unroll
    for (int k=0;k<8;k++){ pe += v[k]*ew[k]; pa += v[k]*aw[k]; pn += v[k]*v[k]; }
#pragma unroll
    for (int off=32; off; off>>=1){
      pe += __shfl_xor(pe, off);
      pa += __shfl_xor(pa, off);
      pn += __shfl_xor(pn, off);
    }
    float inv = 1.0f / fmaxf(sqrtf(pn), 1e-5f);
    eta_sum   += sigmoidf_(pe + eta_b[0]);
    alpha_sum += sigmoidf_(pa + alpha_b[0]);
#pragma unroll
    for (int k=0;k<8;k++){ km_acc[k] += v[k]*inv; xb_acc[k] += v[k]; }
  }

  __shared__ float sKM[4][DIN];
  __shared__ float sXB[4][DIN];
  __shared__ float sEA[4][2];
  __shared__ float sred[4][2];
#pragma unroll
  for (int k=0;k<8;k++){ sKM[wave][lane*8+k]=km_acc[k]; sXB[wave][lane*8+k]=xb_acc[k]; }
  if (lane==0){ sEA[wave][0]=eta_sum; sEA[wave][1]=alpha_sum; }
  __syncthreads();

  float gpart=0.f, km2part=0.f;
  float kmv[2], dvv[2];
#pragma unroll
  for (int k=0;k<2;k++){
    int d = tid*2+k;
    float km = (sKM[0][d]+sKM[1][d]+sKM[2][d]+sKM[3][d]) * (1.0f/64.0f);
    float xb = (sXB[0][d]+sXB[1][d]+sXB[2][d]+sXB[3][d]) * (1.0f/64.0f);
    kmv[k]=km; dvv[k]=xb-km;
    gpart  += km * gate_w[d];
    km2part+= km * km;
  }
#pragma unroll
  for (int off=32; off; off>>=1){
    gpart   += __shfl_xor(gpart, off);
    km2part += __shfl_xor(km2part, off);
  }
  if (lane==0){ sred[wave][0]=gpart; sred[wave][1]=km2part; }
  __syncthreads();

  size_t base = ((size_t)b*NCH + j)*DIN;
#pragma unroll
  for (int k=0;k<2;k++){
    int d = tid*2+k;
    KM[base+d]=kmv[k];
    Dv[base+d]=dvv[k];
    KMh[base+d]=f2bf(kmv[k]);
  }
  if (tid==0){
    float gdot = sred[0][0]+sred[1][0]+sred[2][0]+sred[3][0];
    float km2  = sred[0][1]+sred[1][1]+sred[2][1]+sred[3][1];
    float etam = (sEA[0][0]+sEA[1][0]+sEA[2][0]+sEA[3][0]) * (1.0f/64.0f);
    float alpm = (sEA[0][1]+sEA[1][1]+sEA[2][1]+sEA[3][1]) * (1.0f/64.0f);
    float eta   = 0.2f * etam;
    float alpha = 0.5f + 0.5f * alpm;
    float gate  = sigmoidf_(gdot + gate_b[0]);
    float c1 = gate*alpha + 1.0f - gate;
    float c2 = gate*eta;
    C1[b*NCH+j]  = c1;
    C2[b*NCH+j]  = c2;
    KM2[b*NCH+j] = km2;
    Q[b*NCH+j]   = c2/c1;
  }
}

// ---------------- K2: G0 = D @ M0^T, H0 = KM @ M0^T (o split in halves) ----------------
__global__ __launch_bounds__(256) void k2_g0h0(
    const float* __restrict__ KM, const float* __restrict__ Dv,
    const float* __restrict__ M0, float* __restrict__ G0, float* __restrict__ H0)
{
  int j = blockIdx.x, b = blockIdx.y, half = blockIdx.z;
  __shared__ float sD[DIN], sK[DIN];
  int tid = threadIdx.x;
  size_t base = ((size_t)b*NCH+j)*DIN;
  for (int d=tid; d<DIN; d+=256){ sD[d]=Dv[base+d]; sK[d]=KM[base+d]; }
  __syncthreads();
  int o = half*256 + tid;
  const float* mr = M0 + (size_t)o*DIN;
  float ag=0.f, ah=0.f;
  for (int d=0; d<DIN; d+=4){
    float4 m = *(const float4*)(mr+d);
    ag += m.x*sD[d] + m.y*sD[d+1] + m.z*sD[d+2] + m.w*sD[d+3];
    ah += m.x*sK[d] + m.y*sK[d+1] + m.z*sK[d+2] + m.w*sK[d+3];
  }
  G0[base+o]=ag; H0[base+o]=ah;
}

// ---------------- K2b: Gram matrices, transposed + q-scaled output ----------------
// GT[b][j][i] = q_i * (km_i . d_j), WT[b][j][i] = q_i * (km_i . km_j)
__global__ __launch_bounds__(512) void k2b_gram(
    const float* __restrict__ KM, const float* __restrict__ Dv,
    const float* __restrict__ Q,
    float* __restrict__ GT, float* __restrict__ WT)
{
  int i = blockIdx.x, b = blockIdx.y;
  __shared__ float sKi[DIN];
  int tid = threadIdx.x;
  const float* kmi = KM + ((size_t)b*NCH+i)*DIN;
  for (int d=tid; d<DIN; d+=512) sKi[d]=kmi[d];
  __syncthreads();
  float qi = Q[b*NCH+i];
  int wave = tid>>6, lane = tid&63;
  for (int j=wave; j<NCH; j+=8){
    const float* dj = Dv + ((size_t)b*NCH+j)*DIN;
    const float* kj = KM + ((size_t)b*NCH+j)*DIN;
    float pd=0.f, pk=0.f;
#pragma unroll
    for (int k=0;k<8;k++){
      int d = lane + k*64;
      pd += sKi[d]*dj[d];
      pk += sKi[d]*kj[d];
    }
#pragma unroll
    for (int off=32; off; off>>=1){ pd += __shfl_xor(pd,off); pk += __shfl_xor(pk,off); }
    if (lane==0){
      GT[((size_t)b*NCH+j)*NCH + i] = qi*pd;
      WT[((size_t)b*NCH+j)*NCH + i] = qi*pk;
    }
  }
}

// ---------------- K3a: d-sliced triangular recurrence + dots + UQT pack ----------------
// grid (8, NB), 64 threads (1 wave). Block owns d = dblk*64 + lane.
__global__ __launch_bounds__(64) void k3a_rec(
    const float* __restrict__ G0, const float* __restrict__ H0,
    const float* __restrict__ GT, const float* __restrict__ WT,
    const float* __restrict__ Q,
    float* __restrict__ AU, unsigned short* __restrict__ UQTh, float* __restrict__ DOTS)
{
  int dblk = blockIdx.x, b = blockIdx.y;
  int lane = threadIdx.x;
  int d = dblk*64 + lane;

  __shared__ float sMT[NCH*NCH];
  __shared__ float sWT[NCH*NCH];
  __shared__ float sq[NCH];

  // stage transposed scaled Grams with strict-lower-triangular mask (keep i<j)
  const float4* gt4 = (const float4*)&GT[(size_t)b*NCH*NCH];
  const float4* wt4 = (const float4*)&WT[(size_t)b*NCH*NCH];
#pragma unroll
  for (int t=0;t<16;t++){
    int idx4 = t*64 + lane;       // float4 index
    int idx  = idx4*4;
    int j = idx>>6, i0 = idx&63;
    float4 g = gt4[idx4];
    float4 w = wt4[idx4];
    if (i0+0 >= j){ g.x=0.f; w.x=0.f; }
    if (i0+1 >= j){ g.y=0.f; w.y=0.f; }
    if (i0+2 >= j){ g.z=0.f; w.z=0.f; }
    if (i0+3 >= j){ g.w=0.f; w.w=0.f; }
    *(float4*)&sMT[idx] = g;
    *(float4*)&sWT[idx] = w;
  }
  sq[lane] = Q[b*NCH+lane];
  __syncthreads();

  // preload G0 column slice
  float au[NCH];
  size_t gb = (size_t)b*NCH*DOUT + d;
#pragma unroll
  for (int j=0;j<NCH;j++) au[j] = G0[gb + (size_t)j*DOUT];

  // phase 1: triangular recurrence, b128 row reads (zero-padded tail groups)
#pragma unroll
  for (int j=1;j<NCH;j++){
    float a = au[j];
    const f32x4* row = (const f32x4*)&sMT[j*64];
    int ng = (j+3)>>2;
#pragma unroll
    for (int g=0; g<ng; g++){
      f32x4 c = row[g];
      a += c[0]*au[g*4+0] + c[1]*au[g*4+1] + c[2]*au[g*4+2] + c[3]*au[g*4+3];
    }
    au[j] = a;
  }
#pragma unroll
  for (int j=0;j<NCH;j++) AU[gb + (size_t)j*DOUT] = au[j];

  // UQT pack: row d, 64 bf16 (q_i * au_i)
#pragma unroll
  for (int g=0; g<8; g++){
    uint4 hv;
    hv.x = (unsigned)f2bf(au[g*8+0]*sq[g*8+0]) | ((unsigned)f2bf(au[g*8+1]*sq[g*8+1])<<16);
    hv.y = (unsigned)f2bf(au[g*8+2]*sq[g*8+2]) | ((unsigned)f2bf(au[g*8+3]*sq[g*8+3])<<16);
    hv.z = (unsigned)f2bf(au[g*8+4]*sq[g*8+4]) | ((unsigned)f2bf(au[g*8+5]*sq[g*8+5])<<16);
    hv.w = (unsigned)f2bf(au[g*8+6]*sq[g*8+6]) | ((unsigned)f2bf(au[g*8+7]*sq[g*8+7])<<16);
    *(uint4*)&UQTh[((size_t)b*DOUT + d)*NCH + g*8] = hv;
  }

  // phase 2: w_j and dot partials for this d-slice
#pragma unroll
  for (int j=0;j<NCH;j++){
    float w = H0[gb + (size_t)j*DOUT];
    const f32x4* row = (const f32x4*)&sWT[j*64];
    int ng = (j+3)>>2;
#pragma unroll
    for (int g=0; g<ng; g++){
      f32x4 c = row[g];
      w += c[0]*au[g*4+0] + c[1]*au[g*4+1] + c[2]*au[g*4+2] + c[3]*au[g*4+3];
    }
    float s1 = au[j]*w, s2 = au[j]*au[j];
#pragma unroll
    for (int off=32; off; off>>=1){ s1+=__shfl_xor(s1,off); s2+=__shfl_xor(s2,off); }
    if (lane==0){
      DOTS[(((size_t)b*8+dblk)*NCH+j)*2+0] = s1;
      DOTS[(((size_t)b*8+dblk)*NCH+j)*2+1] = s2;
    }
  }
}

// ---------------- K3b: F0 + combine dot partials + serial p-chain ----------------
__global__ __launch_bounds__(256) void k3b_chain(
    const float* __restrict__ M0, const float* __restrict__ DOTS,
    const float* __restrict__ C1, const float* __restrict__ C2, const float* __restrict__ KM2,
    float* __restrict__ P)
{
  int b = blockIdx.x;
  int tid = threadIdx.x, wave = tid>>6, lane = tid&63;
  __shared__ float sF[4];
  __shared__ float suw[NCH], suu[NCH], sc1[NCH], sc2[NCH], skm2[NCH];

  float f0p = 0.f;
  const float4* m4 = (const float4*)M0;
  for (int i=tid; i<(DOUT*DIN)/4; i+=256){
    float4 v = m4[i];
    f0p += v.x*v.x + v.y*v.y + v.z*v.z + v.w*v.w;
  }
#pragma unroll
  for (int off=32; off; off>>=1) f0p += __shfl_xor(f0p, off);
  if (lane==0) sF[wave]=f0p;

  if (tid < NCH){
    float uw=0.f, uu=0.f;
#pragma unroll
    for (int k=0;k<8;k++){
      uw += DOTS[(((size_t)b*8+k)*NCH+tid)*2+0];
      uu += DOTS[(((size_t)b*8+k)*NCH+tid)*2+1];
    }
    suw[tid]=uw; suu[tid]=uu;
    sc1[tid]=C1[b*NCH+tid]; sc2[tid]=C2[b*NCH+tid]; skm2[tid]=KM2[b*NCH+tid];
  }
  __syncthreads();

  if (tid==0){
    float F = sF[0]+sF[1]+sF[2]+sF[3];
    float p = 1.f;
    P[b*65+0] = 1.f;
    for (int j=0;j<NCH;j++){
      float uw = suw[j], uu = suu[j];
      float c1 = sc1[j], c2 = sc2[j], km2 = skm2[j];
      uw *= p*p; uu *= p*p;
      float Fnew = c1*c1*F + 2.f*c1*c2*uw + c2*c2*uu*km2;
      float scale = fminf(30.0f/(sqrtf(Fnew)+1e-6f), 1.0f);
      F = scale*scale*Fnew;
      p = scale*c1*p;
      P[b*65+j+1] = p;
    }
  }
}

// ---------------- K4: fused out tile 256x64 + in-block S, 8 waves (4x2), XCD-local ----------------
// Computes S = X_tile @ KMh^T in the same K-loop as the main GEMM (shared As),
// then applies the causal-masked correction S @ UQT^T. Replaces k4s_s entirely.
// O-tile is 64 wide so per-wave regs fit in 128 (acc 32 + accS 32 + staging ~30).
#define ASTRIDE 80
__global__ __launch_bounds__(512, 4) void k4_out(
    const float* __restrict__ x, const unsigned short* __restrict__ xh,
    const unsigned short* __restrict__ M0h, const unsigned short* __restrict__ KMh,
    const unsigned short* __restrict__ UQTh,
    const float* __restrict__ P, float* __restrict__ out, int use_xh)
{
  // XCD-locality swizzle: each XCD owns one batch b (4MB xh fits its L2).
  int n = blockIdx.x;                 // 0..1023
  int xcd = n & 7, local = n >> 3;    // local 0..127
  int work = xcd*128 + local;         // bijective
  int ot = work & 7, rb = (work>>3) & 15, b = work >> 7;   // b == xcd

  int tid = threadIdx.x;
  int lane = tid&63, w = tid>>6, m = lane&15, q = lane>>4;
  int wr = w>>1, wc = w&1;
  int O0 = ot*64;
  int R0 = rb*256;

  // pool: As 256xASTRIDE shorts (40960B) + Bs 128xASTRIDE (20480B) = 61440B
  // Bs rows 0..63: M0h O-slice; rows 64..127: KMh (all 64 rows)
  // epilogue reuses pool: per-wave 16x36 floats x 8 = 18432B
  __shared__ __align__(16) char pool[(256+128)*ASTRIDE*2];
  unsigned short* As = (unsigned short*)pool;
  unsigned short* Bs = (unsigned short*)pool + 256*ASTRIDE;
  float* ep = (float*)pool;

  f32x4 acc[4][2];     // main: X @ M0h^T (wave: 64 rows x 32 O-cols)
  f32x4 accS[4][2];    // S: X @ KMh^T (wave: 64 rows x 32 S-cols)
  f32x4 z = {0.f,0.f,0.f,0.f};
#pragma unroll
  for (int mi=0;mi<4;mi++){
#pragma unroll
    for (int nf=0;nf<2;nf++){ acc[mi][nf]=z; accS[mi][nf]=z; }
  }

  // prefetch k0=0 tiles into registers
  uint4 pBM, pBK, pA[4];
  float4 xa[8];
  {
    int il = tid>>3, cc = tid&7;
    pBM = *(const uint4*)&M0h[(size_t)(O0+il)*DIN + 0 + cc*8];
    pBK = *(const uint4*)&KMh[((size_t)b*NCH+il)*DIN + 0 + cc*8];
  }
  if (use_xh){
#pragma unroll
    for (int v=0;v<4;v++){
      int idx=v*512+tid; int row=idx>>3, cc=idx&7;
      pA[v] = *(const uint4*)&xh[((size_t)b*SEQ + R0 + row)*DIN + 0 + cc*8];
    }
  } else {
#pragma unroll
    for (int v=0;v<8;v++){
      int idx=v*512+tid; int row=idx>>4, cc=idx&15;
      xa[v] = *(const float4*)(x + ((size_t)b*SEQ + R0 + row)*DIN + 0 + cc*4);
    }
  }

  // ---- main K loop: acc += X @ M0h^T ; accS += X @ KMh^T ----
  for (int k0=0;k0<DIN;k0+=64){
    __syncthreads();                 // previous MFMA done reading As/Bs
    {
      int il = tid>>3, cc = tid&7;
      *(uint4*)&Bs[il*ASTRIDE + cc*8] = pBM;
      *(uint4*)&Bs[(64+il)*ASTRIDE + cc*8] = pBK;
    }
    if (use_xh){
#pragma unroll
      for (int v=0;v<4;v++){
        int idx=v*512+tid; int row=idx>>3, cc=idx&7;
        *(uint4*)&As[row*ASTRIDE + cc*8] = pA[v];
      }
    } else {
#pragma unroll
      for (int v=0;v<8;v++){
        int idx=v*512+tid; int row=idx>>4, cc=idx&15;
        store_bf4(&As[row*ASTRIDE + cc*4], xa[v]);
      }
    }
    // prefetch next k-tile (latency hides under MFMA below)
    int kn = k0 + 64;
    if (kn < DIN){
      {
        int il = tid>>3, cc = tid&7;
        pBM = *(const uint4*)&M0h[(size_t)(O0+il)*DIN + kn + cc*8];
        pBK = *(const uint4*)&KMh[((size_t)b*NCH+il)*DIN + kn + cc*8];
      }
      if (use_xh){
#pragma unroll
        for (int v=0;v<4;v++){
          int idx=v*512+tid; int row=idx>>3, cc=idx&7;
          pA[v] = *(const uint4*)&xh[((size_t)b*SEQ + R0 + row)*DIN + kn + cc*8];
        }
      } else {
#pragma unroll
        for (int v=0;v<8;v++){
          int idx=v*512+tid; int row=idx>>4, cc=idx&15;
          xa[v] = *(const float4*)(x + ((size_t)b*SEQ + R0 + row)*DIN + kn + cc*4);
        }
      }
    }
    __syncthreads();
#pragma unroll
    for (int kk=0;kk<2;kk++){
#pragma unroll
      for (int mi=0;mi<4;mi++){
        bh8_t af = *(bh8_t*)&As[(wr*64+mi*16+m)*ASTRIDE + kk*32 + q*8];
#pragma unroll
        for (int nf=0;nf<2;nf++){
          bh8_t bf_ = *(bh8_t*)&Bs[(wc*32+nf*16+m)*ASTRIDE + kk*32 + q*8];
          acc[mi][nf] = __builtin_amdgcn_mfma_f32_16x16x32_bf16(af, bf_, acc[mi][nf], 0,0,0);
          bh8_t bs_ = *(bh8_t*)&Bs[(64+wc*32+nf*16+m)*ASTRIDE + kk*32 + q*8];
          accS[mi][nf] = __builtin_amdgcn_mfma_f32_16x16x32_bf16(af, bs_, accS[mi][nf], 0,0,0);
        }
      }
    }
  }

  // ---- correction setup: masked bf16 S -> As, UQT slice -> Bs ----
  __syncthreads();                    // all K-loop MFMAs done
  {
    int il = tid>>3, cc = tid&7;      // 64 rows x 8 granules
    *(uint4*)&Bs[il*ASTRIDE + cc*8] = *(const uint4*)&UQTh[((size_t)b*DOUT + O0+il)*NCH + cc*8];
  }
  // S fragment: row_local = mi*16 + q*4 + r (within wave's 64 rows), col i = wc*32 + nf*16 + m
#pragma unroll
  for (int mi=0;mi<4;mi++){
#pragma unroll
    for (int nf=0;nf<2;nf++){
      int i = wc*32 + nf*16 + m;
#pragma unroll
      for (int r=0;r<4;r++){
        int rloc = wr*64 + mi*16 + q*4 + r;
        int j = (R0 + rloc)>>6;       // chunk of this x-row
        unsigned short hv = (i < j) ? f2bf(accS[mi][nf][r]) : (unsigned short)0;
        As[rloc*ASTRIDE + i] = hv;
      }
    }
  }
  __syncthreads();
  // correction MFMA: acc += S_masked @ UQT^T
#pragma unroll
  for (int kk=0;kk<2;kk++){
#pragma unroll
    for (int mi=0;mi<4;mi++){
      bh8_t af = *(bh8_t*)&As[(wr*64+mi*16+m)*ASTRIDE + kk*32 + q*8];
#pragma unroll
      for (int nf=0;nf<2;nf++){
        bh8_t bf_ = *(bh8_t*)&Bs[(wc*32+nf*16+m)*ASTRIDE + kk*32 + q*8];
        acc[mi][nf] = __builtin_amdgcn_mfma_f32_16x16x32_bf16(af, bf_, acc[mi][nf], 0,0,0);
      }
    }
  }

  // ---- epilogue: per-wave transpose, p-scale, nontemporal coalesced stores ----
  __syncthreads();                       // all MFMAs done before pool reuse
  float p = P[b*65 + rb*4 + wr];         // wave's 64 rows all in chunk rb*4+wr
  float* epw = ep + w*(16*36);
#pragma unroll
  for (int mi=0; mi<4; mi++){
#pragma unroll
    for (int nf=0;nf<2;nf++)
#pragma unroll
      for (int r=0;r<4;r++)
        epw[(q*4+r)*36 + nf*16 + m] = p*acc[mi][nf][r];
    // per-wave scratch: in-order LDS within wave, no cross-wave barrier needed
#pragma unroll
    for (int v=0;v<2;v++){
      int idx = v*64 + lane;
      int row = idx>>3, c4 = idx&7;
      f32x4 vv = *(f32x4*)&epw[row*36 + c4*4];
      f32x4* pdst = (f32x4*)&out[((size_t)b*SEQ + R0 + wr*64 + mi*16 + row)*DOUT + O0 + wc*32 + c4*4];
      __builtin_nontemporal_store(vv, pdst);
    }
  }
}

// ---------------- K5: M_fin = p64*(M0 + sum_i q_i AU_i km_i^T) ----------------
__global__ __launch_bounds__(256) void k5_mfin(
    const float* __restrict__ M0, const float* __restrict__ KM,
    const float* __restrict__ AU, const float* __restrict__ P, const float* __restrict__ Q,
    float* __restrict__ Mout)
{
  int ob = blockIdx.x, b = blockIdx.y;
  int tid = threadIdx.x;
  __shared__ float uo[64][8];
  for (int idx=tid; idx<512; idx+=256){
    int i = idx>>3, oo = idx&7;
    uo[i][oo] = Q[b*NCH+i] * AU[((size_t)b*NCH+i)*DOUT + ob*8+oo];
  }
  __syncthreads();
  float p64 = P[b*65+NCH];
  float acc[2][8];
#pragma unroll
  for (int h=0;h<2;h++)
#pragma unroll
    for (int oo=0;oo<8;oo++) acc[h][oo]=0.f;
  int d0 = tid, d1 = tid+256;
  for (int i=0;i<64;i++){
    float k0 = KM[((size_t)b*NCH+i)*DIN + d0];
    float k1 = KM[((size_t)b*NCH+i)*DIN + d1];
#pragma unroll
    for (int oo=0;oo<8;oo++){
      float u = uo[i][oo];
      acc[0][oo] += u*k0;
      acc[1][oo] += u*k1;
    }
  }
#pragma unroll
  for (int oo=0;oo<8;oo++){
    int o = ob*8+oo;
    Mout[((size_t)b*DOUT + o)*DIN + d0] = p64*(M0[(size_t)o*DIN+d0] + acc[0][oo]);
    Mout[((size_t)b*DOUT + o)*DIN + d1] = p64*(M0[(size_t)o*DIN+d1] + acc[1][oo]);
  }
}

// ---------------- launch ----------------
extern "C" void kernel_launch(void* const* d_in, const int* in_sizes, int n_in,
                              void* d_out, int out_size, void* d_ws, size_t ws_size,
                              hipStream_t stream) {
  const float* x       = (const float*)d_in[0];
  const float* M0      = (const float*)d_in[1];
  const float* eta_w   = (const float*)d_in[2];
  const float* eta_b   = (const float*)d_in[3];
  const float* alpha_w = (const float*)d_in[4];
  const float* alpha_b = (const float*)d_in[5];
  const float* gate_w  = (const float*)d_in[6];
  const float* gate_b  = (const float*)d_in[7];
  float* out = (float*)d_out;

  float* ws = (float*)d_ws;
  // fp32 region
  float* KM   = ws;                    // 262144
  float* Dv   = KM   + 262144;
  float* G0   = Dv   + 262144;
  float* H0   = G0   + 262144;
  float* AU   = H0   + 262144;
  float* GT   = AU   + 262144;         // 32768 (transposed q-scaled KMD)
  float* WT   = GT   + 32768;          // 32768 (transposed q-scaled KMKM)
  float* C1   = WT   + 32768;          // 512
  float* C2   = C1   + 512;
  float* KM2  = C2   + 512;
  float* Q    = KM2  + 512;
  float* P    = Q    + 512;            // 1024 (8*65 used)
  float* DOTS = P    + 1024;           // 8192 (NB*8*64*2)
  // bf16 region
  unsigned short* M0h  = (unsigned short*)(DOTS + 8192);   // 262144 shorts
  unsigned short* KMh  = M0h  + 262144;                    // 262144
  unsigned short* Sh   = KMh  + 262144;                    // 2097152 (unused; kept for layout)
  unsigned short* UQTh = Sh   + 2097152;                   // 262144
  unsigned short* xh   = UQTh + 262144;                    // 16777216 (optional)

  size_t base_bytes = (size_t)((char*)xh - (char*)d_ws);
  size_t need_xh = base_bytes + (size_t)16777216*2;
  int use_xh = (ws_size >= need_xh) ? 1 : 0;
  unsigned short* xh_arg = use_xh ? xh : (unsigned short*)0;

  k0_m0h<<<dim3(256), 256, 0, stream>>>(M0, M0h);
  k1_stats<<<dim3(NCH, NB), 256, 0, stream>>>(x, eta_w, eta_b, alpha_w, alpha_b,
                                              gate_w, gate_b, KM, Dv, KMh, C1, C2, KM2, Q, xh_arg);
  k2_g0h0<<<dim3(NCH, NB, 2), 256, 0, stream>>>(KM, Dv, M0, G0, H0);
  k2b_gram<<<dim3(NCH, NB), 512, 0, stream>>>(KM, Dv, Q, GT, WT);
  k3a_rec<<<dim3(8, NB), 64, 0, stream>>>(G0, H0, GT, WT, Q, AU, UQTh, DOTS);
  k3b_chain<<<dim3(NB), 256, 0, stream>>>(M0, DOTS, C1, C2, KM2, P);
  k4_out<<<dim3(1024), 512, 0, stream>>>(x, xh, M0h, KMh, UQTh, P, out, use_xh);
  k5_mfin<<<dim3(64, NB), 256, 0, stream>>>(M0, KM, AU, P, Q, out + (size_t)NB*SEQ*DOUT);
}

// Round 11
// 427.994 us; speedup vs baseline: 1.2868x; 1.1993x over previous
//
#include <hip/hip_runtime.h>
#include <math.h>

#define DIN  512
#define DOUT 512
#define CHK  64
#define NCH  64
#define NB   8
#define SEQ  4096

typedef short bh8_t __attribute__((ext_vector_type(8)));
typedef float f32x4 __attribute__((ext_vector_type(4)));

__device__ __forceinline__ float sigmoidf_(float z){ return 1.0f/(1.0f+__expf(-z)); }

__device__ __forceinline__ unsigned short f2bf(float f){
  unsigned u = __float_as_uint(f);
  unsigned r = (u + 0x7fffu + ((u>>16)&1u)) >> 16;
  return (unsigned short)r;
}
__device__ __forceinline__ void store_bf4(unsigned short* p, float4 v){
  uint2 u;
  u.x = (unsigned)f2bf(v.x) | ((unsigned)f2bf(v.y)<<16);
  u.y = (unsigned)f2bf(v.z) | ((unsigned)f2bf(v.w)<<16);
  *(uint2*)p = u;
}

// ---------------- K0: M0 -> bf16 ----------------
__global__ __launch_bounds__(256) void k0_m0h(const float* __restrict__ M0, unsigned short* __restrict__ M0h){
  int idx = (blockIdx.x*256 + threadIdx.x)*4;
  float4 v = *(const float4*)(M0+idx);
  store_bf4(M0h+idx, v);
}

// ---------------- K1: per-(batch,chunk) statistics (+ x -> bf16) ----------------
__global__ __launch_bounds__(256) void k1_stats(
    const float* __restrict__ x,
    const float* __restrict__ eta_w, const float* __restrict__ eta_b,
    const float* __restrict__ alpha_w, const float* __restrict__ alpha_b,
    const float* __restrict__ gate_w, const float* __restrict__ gate_b,
    float* __restrict__ KM, float* __restrict__ Dv, unsigned short* __restrict__ KMh,
    float* __restrict__ C1, float* __restrict__ C2, float* __restrict__ KM2, float* __restrict__ Q,
    unsigned short* __restrict__ xh)
{
  int j = blockIdx.x, b = blockIdx.y;
  const float* xc = x + ((size_t)b*SEQ + (size_t)j*CHK) * DIN;
  int tid = threadIdx.x;
  int wave = tid >> 6, lane = tid & 63;

  float km_acc[8], xb_acc[8];
#pragma unroll
  for (int k=0;k<8;k++){ km_acc[k]=0.f; xb_acc[k]=0.f; }
  float eta_sum = 0.f, alpha_sum = 0.f;
  float ew[8], aw[8];
#pragma unroll
  for (int k=0;k<8;k++){ ew[k]=eta_w[lane*8+k]; aw[k]=alpha_w[lane*8+k]; }

  for (int tt=0; tt<16; tt++){
    int t = wave*16 + tt;
    const float* xr = xc + (size_t)t*DIN + lane*8;
    float v[8];
#pragma unroll
    for (int k=0;k<8;k++) v[k]=xr[k];
    if (xh){
      uint4 hv;
      hv.x = (unsigned)f2bf(v[0]) | ((unsigned)f2bf(v[1])<<16);
      hv.y = (unsigned)f2bf(v[2]) | ((unsigned)f2bf(v[3])<<16);
      hv.z = (unsigned)f2bf(v[4]) | ((unsigned)f2bf(v[5])<<16);
      hv.w = (unsigned)f2bf(v[6]) | ((unsigned)f2bf(v[7])<<16);
      *(uint4*)&xh[((size_t)b*SEQ + (size_t)j*CHK + t)*DIN + lane*8] = hv;
    }
    float pe=0.f, pa=0.f, pn=0.f;
#pragma unroll
    for (int k=0;k<8;k++){ pe += v[k]*ew[k]; pa += v[k]*aw[k]; pn += v[k]*v[k]; }
#pragma unroll
    for (int off=32; off; off>>=1){
      pe += __shfl_xor(pe, off);
      pa += __shfl_xor(pa, off);
      pn += __shfl_xor(pn, off);
    }
    float inv = 1.0f / fmaxf(sqrtf(pn), 1e-5f);
    eta_sum   += sigmoidf_(pe + eta_b[0]);
    alpha_sum += sigmoidf_(pa + alpha_b[0]);
#pragma unroll
    for (int k=0;k<8;k++){ km_acc[k] += v[k]*inv; xb_acc[k] += v[k]; }
  }

  __shared__ float sKM[4][DIN];
  __shared__ float sXB[4][DIN];
  __shared__ float sEA[4][2];
  __shared__ float sred[4][2];
#pragma unroll
  for (int k=0;k<8;k++){ sKM[wave][lane*8+k]=km_acc[k]; sXB[wave][lane*8+k]=xb_acc[k]; }
  if (lane==0){ sEA[wave][0]=eta_sum; sEA[wave][1]=alpha_sum; }
  __syncthreads();

  float gpart=0.f, km2part=0.f;
  float kmv[2], dvv[2];
#pragma unroll
  for (int k=0;k<2;k++){
    int d = tid*2+k;
    float km = (sKM[0][d]+sKM[1][d]+sKM[2][d]+sKM[3][d]) * (1.0f/64.0f);
    float xb = (sXB[0][d]+sXB[1][d]+sXB[2][d]+sXB[3][d]) * (1.0f/64.0f);
    kmv[k]=km; dvv[k]=xb-km;
    gpart  += km * gate_w[d];
    km2part+= km * km;
  }
#pragma unroll
  for (int off=32; off; off>>=1){
    gpart   += __shfl_xor(gpart, off);
    km2part += __shfl_xor(km2part, off);
  }
  if (lane==0){ sred[wave][0]=gpart; sred[wave][1]=km2part; }
  __syncthreads();

  size_t base = ((size_t)b*NCH + j)*DIN;
#pragma unroll
  for (int k=0;k<2;k++){
    int d = tid*2+k;
    KM[base+d]=kmv[k];
    Dv[base+d]=dvv[k];
    KMh[base+d]=f2bf(kmv[k]);
  }
  if (tid==0){
    float gdot = sred[0][0]+sred[1][0]+sred[2][0]+sred[3][0];
    float km2  = sred[0][1]+sred[1][1]+sred[2][1]+sred[3][1];
    float etam = (sEA[0][0]+sEA[1][0]+sEA[2][0]+sEA[3][0]) * (1.0f/64.0f);
    float alpm = (sEA[0][1]+sEA[1][1]+sEA[2][1]+sEA[3][1]) * (1.0f/64.0f);
    float eta   = 0.2f * etam;
    float alpha = 0.5f + 0.5f * alpm;
    float gate  = sigmoidf_(gdot + gate_b[0]);
    float c1 = gate*alpha + 1.0f - gate;
    float c2 = gate*eta;
    C1[b*NCH+j]  = c1;
    C2[b*NCH+j]  = c2;
    KM2[b*NCH+j] = km2;
    Q[b*NCH+j]   = c2/c1;
  }
}

// ---------------- K2: G0 = D @ M0^T, H0 = KM @ M0^T (o split in halves) ----------------
__global__ __launch_bounds__(256) void k2_g0h0(
    const float* __restrict__ KM, const float* __restrict__ Dv,
    const float* __restrict__ M0, float* __restrict__ G0, float* __restrict__ H0)
{
  int j = blockIdx.x, b = blockIdx.y, half = blockIdx.z;
  __shared__ float sD[DIN], sK[DIN];
  int tid = threadIdx.x;
  size_t base = ((size_t)b*NCH+j)*DIN;
  for (int d=tid; d<DIN; d+=256){ sD[d]=Dv[base+d]; sK[d]=KM[base+d]; }
  __syncthreads();
  int o = half*256 + tid;
  const float* mr = M0 + (size_t)o*DIN;
  float ag=0.f, ah=0.f;
  for (int d=0; d<DIN; d+=4){
    float4 m = *(const float4*)(mr+d);
    ag += m.x*sD[d] + m.y*sD[d+1] + m.z*sD[d+2] + m.w*sD[d+3];
    ah += m.x*sK[d] + m.y*sK[d+1] + m.z*sK[d+2] + m.w*sK[d+3];
  }
  G0[base+o]=ag; H0[base+o]=ah;
}

// ---------------- K2b: Gram matrices, transposed + q-scaled output ----------------
// GT[b][j][i] = q_i * (km_i . d_j), WT[b][j][i] = q_i * (km_i . km_j)
__global__ __launch_bounds__(512) void k2b_gram(
    const float* __restrict__ KM, const float* __restrict__ Dv,
    const float* __restrict__ Q,
    float* __restrict__ GT, float* __restrict__ WT)
{
  int i = blockIdx.x, b = blockIdx.y;
  __shared__ float sKi[DIN];
  int tid = threadIdx.x;
  const float* kmi = KM + ((size_t)b*NCH+i)*DIN;
  for (int d=tid; d<DIN; d+=512) sKi[d]=kmi[d];
  __syncthreads();
  float qi = Q[b*NCH+i];
  int wave = tid>>6, lane = tid&63;
  for (int j=wave; j<NCH; j+=8){
    const float* dj = Dv + ((size_t)b*NCH+j)*DIN;
    const float* kj = KM + ((size_t)b*NCH+j)*DIN;
    float pd=0.f, pk=0.f;
#pragma unroll
    for (int k=0;k<8;k++){
      int d = lane + k*64;
      pd += sKi[d]*dj[d];
      pk += sKi[d]*kj[d];
    }
#pragma unroll
    for (int off=32; off; off>>=1){ pd += __shfl_xor(pd,off); pk += __shfl_xor(pk,off); }
    if (lane==0){
      GT[((size_t)b*NCH+j)*NCH + i] = qi*pd;
      WT[((size_t)b*NCH+j)*NCH + i] = qi*pk;
    }
  }
}

// ---------------- K3a: d-sliced triangular recurrence + dots + UQT pack ----------------
// grid (8, NB), 64 threads (1 wave). Block owns d = dblk*64 + lane.
__global__ __launch_bounds__(64) void k3a_rec(
    const float* __restrict__ G0, const float* __restrict__ H0,
    const float* __restrict__ GT, const float* __restrict__ WT,
    const float* __restrict__ Q,
    float* __restrict__ AU, unsigned short* __restrict__ UQTh, float* __restrict__ DOTS)
{
  int dblk = blockIdx.x, b = blockIdx.y;
  int lane = threadIdx.x;
  int d = dblk*64 + lane;

  __shared__ float sMT[NCH*NCH];
  __shared__ float sWT[NCH*NCH];
  __shared__ float sq[NCH];

  // stage transposed scaled Grams with strict-lower-triangular mask (keep i<j)
  const float4* gt4 = (const float4*)&GT[(size_t)b*NCH*NCH];
  const float4* wt4 = (const float4*)&WT[(size_t)b*NCH*NCH];
#pragma unroll
  for (int t=0;t<16;t++){
    int idx4 = t*64 + lane;       // float4 index
    int idx  = idx4*4;
    int j = idx>>6, i0 = idx&63;
    float4 g = gt4[idx4];
    float4 w = wt4[idx4];
    if (i0+0 >= j){ g.x=0.f; w.x=0.f; }
    if (i0+1 >= j){ g.y=0.f; w.y=0.f; }
    if (i0+2 >= j){ g.z=0.f; w.z=0.f; }
    if (i0+3 >= j){ g.w=0.f; w.w=0.f; }
    *(float4*)&sMT[idx] = g;
    *(float4*)&sWT[idx] = w;
  }
  sq[lane] = Q[b*NCH+lane];
  __syncthreads();

  // preload G0 column slice
  float au[NCH];
  size_t gb = (size_t)b*NCH*DOUT + d;
#pragma unroll
  for (int j=0;j<NCH;j++) au[j] = G0[gb + (size_t)j*DOUT];

  // phase 1: triangular recurrence, b128 row reads (zero-padded tail groups)
#pragma unroll
  for (int j=1;j<NCH;j++){
    float a = au[j];
    const f32x4* row = (const f32x4*)&sMT[j*64];
    int ng = (j+3)>>2;
#pragma unroll
    for (int g=0; g<ng; g++){
      f32x4 c = row[g];
      a += c[0]*au[g*4+0] + c[1]*au[g*4+1] + c[2]*au[g*4+2] + c[3]*au[g*4+3];
    }
    au[j] = a;
  }
#pragma unroll
  for (int j=0;j<NCH;j++) AU[gb + (size_t)j*DOUT] = au[j];

  // UQT pack: row d, 64 bf16 (q_i * au_i)
#pragma unroll
  for (int g=0; g<8; g++){
    uint4 hv;
    hv.x = (unsigned)f2bf(au[g*8+0]*sq[g*8+0]) | ((unsigned)f2bf(au[g*8+1]*sq[g*8+1])<<16);
    hv.y = (unsigned)f2bf(au[g*8+2]*sq[g*8+2]) | ((unsigned)f2bf(au[g*8+3]*sq[g*8+3])<<16);
    hv.z = (unsigned)f2bf(au[g*8+4]*sq[g*8+4]) | ((unsigned)f2bf(au[g*8+5]*sq[g*8+5])<<16);
    hv.w = (unsigned)f2bf(au[g*8+6]*sq[g*8+6]) | ((unsigned)f2bf(au[g*8+7]*sq[g*8+7])<<16);
    *(uint4*)&UQTh[((size_t)b*DOUT + d)*NCH + g*8] = hv;
  }

  // phase 2: w_j and dot partials for this d-slice
#pragma unroll
  for (int j=0;j<NCH;j++){
    float w = H0[gb + (size_t)j*DOUT];
    const f32x4* row = (const f32x4*)&sWT[j*64];
    int ng = (j+3)>>2;
#pragma unroll
    for (int g=0; g<ng; g++){
      f32x4 c = row[g];
      w += c[0]*au[g*4+0] + c[1]*au[g*4+1] + c[2]*au[g*4+2] + c[3]*au[g*4+3];
    }
    float s1 = au[j]*w, s2 = au[j]*au[j];
#pragma unroll
    for (int off=32; off; off>>=1){ s1+=__shfl_xor(s1,off); s2+=__shfl_xor(s2,off); }
    if (lane==0){
      DOTS[(((size_t)b*8+dblk)*NCH+j)*2+0] = s1;
      DOTS[(((size_t)b*8+dblk)*NCH+j)*2+1] = s2;
    }
  }
}

// ---------------- K3b: F0 + combine dot partials + serial p-chain ----------------
__global__ __launch_bounds__(256) void k3b_chain(
    const float* __restrict__ M0, const float* __restrict__ DOTS,
    const float* __restrict__ C1, const float* __restrict__ C2, const float* __restrict__ KM2,
    float* __restrict__ P)
{
  int b = blockIdx.x;
  int tid = threadIdx.x, wave = tid>>6, lane = tid&63;
  __shared__ float sF[4];
  __shared__ float suw[NCH], suu[NCH], sc1[NCH], sc2[NCH], skm2[NCH];

  float f0p = 0.f;
  const float4* m4 = (const float4*)M0;
  for (int i=tid; i<(DOUT*DIN)/4; i+=256){
    float4 v = m4[i];
    f0p += v.x*v.x + v.y*v.y + v.z*v.z + v.w*v.w;
  }
#pragma unroll
  for (int off=32; off; off>>=1) f0p += __shfl_xor(f0p, off);
  if (lane==0) sF[wave]=f0p;

  if (tid < NCH){
    float uw=0.f, uu=0.f;
#pragma unroll
    for (int k=0;k<8;k++){
      uw += DOTS[(((size_t)b*8+k)*NCH+tid)*2+0];
      uu += DOTS[(((size_t)b*8+k)*NCH+tid)*2+1];
    }
    suw[tid]=uw; suu[tid]=uu;
    sc1[tid]=C1[b*NCH+tid]; sc2[tid]=C2[b*NCH+tid]; skm2[tid]=KM2[b*NCH+tid];
  }
  __syncthreads();

  if (tid==0){
    float F = sF[0]+sF[1]+sF[2]+sF[3];
    float p = 1.f;
    P[b*65+0] = 1.f;
    for (int j=0;j<NCH;j++){
      float uw = suw[j], uu = suu[j];
      float c1 = sc1[j], c2 = sc2[j], km2 = skm2[j];
      uw *= p*p; uu *= p*p;
      float Fnew = c1*c1*F + 2.f*c1*c2*uw + c2*c2*uu*km2;
      float scale = fminf(30.0f/(sqrtf(Fnew)+1e-6f), 1.0f);
      F = scale*scale*Fnew;
      p = scale*c1*p;
      P[b*65+j+1] = p;
    }
  }
}

// ---------------- K4: fused out tile 256x64 + in-block S, 8 waves (4x2), XCD-local ----------------
// Computes S = X_tile @ KMh^T in the same K-loop as the main GEMM (shared As),
// then applies the causal-masked correction S @ UQT^T. Replaces k4s_s entirely.
// NOTE: no min-occupancy clamp — (512,4) capped VGPRs at 64 and spilled the
// accumulators to scratch (698 MB WRITE_SIZE). Let the allocator take ~130.
#define ASTRIDE 80
__global__ __launch_bounds__(512) void k4_out(
    const float* __restrict__ x, const unsigned short* __restrict__ xh,
    const unsigned short* __restrict__ M0h, const unsigned short* __restrict__ KMh,
    const unsigned short* __restrict__ UQTh,
    const float* __restrict__ P, float* __restrict__ out, int use_xh)
{
  // XCD-locality swizzle: each XCD owns one batch b (4MB xh fits its L2).
  int n = blockIdx.x;                 // 0..1023
  int xcd = n & 7, local = n >> 3;    // local 0..127
  int work = xcd*128 + local;         // bijective
  int ot = work & 7, rb = (work>>3) & 15, b = work >> 7;   // b == xcd

  int tid = threadIdx.x;
  int lane = tid&63, w = tid>>6, m = lane&15, q = lane>>4;
  int wr = w>>1, wc = w&1;
  int O0 = ot*64;
  int R0 = rb*256;

  // pool: As 256xASTRIDE shorts (40960B) + Bs 128xASTRIDE (20480B) = 61440B
  // Bs rows 0..63: M0h O-slice; rows 64..127: KMh (all 64 rows)
  // epilogue reuses pool: per-wave 16x36 floats x 8 = 18432B
  __shared__ __align__(16) char pool[(256+128)*ASTRIDE*2];
  unsigned short* As = (unsigned short*)pool;
  unsigned short* Bs = (unsigned short*)pool + 256*ASTRIDE;
  float* ep = (float*)pool;

  f32x4 acc[4][2];     // main: X @ M0h^T (wave: 64 rows x 32 O-cols)
  f32x4 accS[4][2];    // S: X @ KMh^T (wave: 64 rows x 32 S-cols)
  f32x4 z = {0.f,0.f,0.f,0.f};
#pragma unroll
  for (int mi=0;mi<4;mi++){
#pragma unroll
    for (int nf=0;nf<2;nf++){ acc[mi][nf]=z; accS[mi][nf]=z; }
  }

  // prefetch k0=0 tiles into registers
  uint4 pBM, pBK, pA[4];
  float4 xa[8];
  {
    int il = tid>>3, cc = tid&7;
    pBM = *(const uint4*)&M0h[(size_t)(O0+il)*DIN + 0 + cc*8];
    pBK = *(const uint4*)&KMh[((size_t)b*NCH+il)*DIN + 0 + cc*8];
  }
  if (use_xh){
#pragma unroll
    for (int v=0;v<4;v++){
      int idx=v*512+tid; int row=idx>>3, cc=idx&7;
      pA[v] = *(const uint4*)&xh[((size_t)b*SEQ + R0 + row)*DIN + 0 + cc*8];
    }
  } else {
#pragma unroll
    for (int v=0;v<8;v++){
      int idx=v*512+tid; int row=idx>>4, cc=idx&15;
      xa[v] = *(const float4*)(x + ((size_t)b*SEQ + R0 + row)*DIN + 0 + cc*4);
    }
  }

  // ---- main K loop: acc += X @ M0h^T ; accS += X @ KMh^T ----
  for (int k0=0;k0<DIN;k0+=64){
    __syncthreads();                 // previous MFMA done reading As/Bs
    {
      int il = tid>>3, cc = tid&7;
      *(uint4*)&Bs[il*ASTRIDE + cc*8] = pBM;
      *(uint4*)&Bs[(64+il)*ASTRIDE + cc*8] = pBK;
    }
    if (use_xh){
#pragma unroll
      for (int v=0;v<4;v++){
        int idx=v*512+tid; int row=idx>>3, cc=idx&7;
        *(uint4*)&As[row*ASTRIDE + cc*8] = pA[v];
      }
    } else {
#pragma unroll
      for (int v=0;v<8;v++){
        int idx=v*512+tid; int row=idx>>4, cc=idx&15;
        store_bf4(&As[row*ASTRIDE + cc*4], xa[v]);
      }
    }
    // prefetch next k-tile (latency hides under MFMA below)
    int kn = k0 + 64;
    if (kn < DIN){
      {
        int il = tid>>3, cc = tid&7;
        pBM = *(const uint4*)&M0h[(size_t)(O0+il)*DIN + kn + cc*8];
        pBK = *(const uint4*)&KMh[((size_t)b*NCH+il)*DIN + kn + cc*8];
      }
      if (use_xh){
#pragma unroll
        for (int v=0;v<4;v++){
          int idx=v*512+tid; int row=idx>>3, cc=idx&7;
          pA[v] = *(const uint4*)&xh[((size_t)b*SEQ + R0 + row)*DIN + kn + cc*8];
        }
      } else {
#pragma unroll
        for (int v=0;v<8;v++){
          int idx=v*512+tid; int row=idx>>4, cc=idx&15;
          xa[v] = *(const float4*)(x + ((size_t)b*SEQ + R0 + row)*DIN + kn + cc*4);
        }
      }
    }
    __syncthreads();
#pragma unroll
    for (int kk=0;kk<2;kk++){
#pragma unroll
      for (int mi=0;mi<4;mi++){
        bh8_t af = *(bh8_t*)&As[(wr*64+mi*16+m)*ASTRIDE + kk*32 + q*8];
#pragma unroll
        for (int nf=0;nf<2;nf++){
          bh8_t bf_ = *(bh8_t*)&Bs[(wc*32+nf*16+m)*ASTRIDE + kk*32 + q*8];
          acc[mi][nf] = __builtin_amdgcn_mfma_f32_16x16x32_bf16(af, bf_, acc[mi][nf], 0,0,0);
          bh8_t bs_ = *(bh8_t*)&Bs[(64+wc*32+nf*16+m)*ASTRIDE + kk*32 + q*8];
          accS[mi][nf] = __builtin_amdgcn_mfma_f32_16x16x32_bf16(af, bs_, accS[mi][nf], 0,0,0);
        }
      }
    }
  }

  // ---- correction setup: masked bf16 S -> As, UQT slice -> Bs ----
  __syncthreads();                    // all K-loop MFMAs done
  {
    int il = tid>>3, cc = tid&7;      // 64 rows x 8 granules
    *(uint4*)&Bs[il*ASTRIDE + cc*8] = *(const uint4*)&UQTh[((size_t)b*DOUT + O0+il)*NCH + cc*8];
  }
  // S fragment: row_local = mi*16 + q*4 + r (within wave's 64 rows), col i = wc*32 + nf*16 + m
#pragma unroll
  for (int mi=0;mi<4;mi++){
#pragma unroll
    for (int nf=0;nf<2;nf++){
      int i = wc*32 + nf*16 + m;
#pragma unroll
      for (int r=0;r<4;r++){
        int rloc = wr*64 + mi*16 + q*4 + r;
        int j = (R0 + rloc)>>6;       // chunk of this x-row
        unsigned short hv = (i < j) ? f2bf(accS[mi][nf][r]) : (unsigned short)0;
        As[rloc*ASTRIDE + i] = hv;
      }
    }
  }
  __syncthreads();
  // correction MFMA: acc += S_masked @ UQT^T
#pragma unroll
  for (int kk=0;kk<2;kk++){
#pragma unroll
    for (int mi=0;mi<4;mi++){
      bh8_t af = *(bh8_t*)&As[(wr*64+mi*16+m)*ASTRIDE + kk*32 + q*8];
#pragma unroll
      for (int nf=0;nf<2;nf++){
        bh8_t bf_ = *(bh8_t*)&Bs[(wc*32+nf*16+m)*ASTRIDE + kk*32 + q*8];
        acc[mi][nf] = __builtin_amdgcn_mfma_f32_16x16x32_bf16(af, bf_, acc[mi][nf], 0,0,0);
      }
    }
  }

  // ---- epilogue: per-wave transpose, p-scale, nontemporal coalesced stores ----
  __syncthreads();                       // all MFMAs done before pool reuse
  float p = P[b*65 + rb*4 + wr];         // wave's 64 rows all in chunk rb*4+wr
  float* epw = ep + w*(16*36);
#pragma unroll
  for (int mi=0; mi<4; mi++){
#pragma unroll
    for (int nf=0;nf<2;nf++)
#pragma unroll
      for (int r=0;r<4;r++)
        epw[(q*4+r)*36 + nf*16 + m] = p*acc[mi][nf][r];
    // per-wave scratch: in-order LDS within wave, no cross-wave barrier needed
#pragma unroll
    for (int v=0;v<2;v++){
      int idx = v*64 + lane;
      int row = idx>>3, c4 = idx&7;
      f32x4 vv = *(f32x4*)&epw[row*36 + c4*4];
      f32x4* pdst = (f32x4*)&out[((size_t)b*SEQ + R0 + wr*64 + mi*16 + row)*DOUT + O0 + wc*32 + c4*4];
      __builtin_nontemporal_store(vv, pdst);
    }
  }
}

// ---------------- K5: M_fin = p64*(M0 + sum_i q_i AU_i km_i^T) ----------------
__global__ __launch_bounds__(256) void k5_mfin(
    const float* __restrict__ M0, const float* __restrict__ KM,
    const float* __restrict__ AU, const float* __restrict__ P, const float* __restrict__ Q,
    float* __restrict__ Mout)
{
  int ob = blockIdx.x, b = blockIdx.y;
  int tid = threadIdx.x;
  __shared__ float uo[64][8];
  for (int idx=tid; idx<512; idx+=256){
    int i = idx>>3, oo = idx&7;
    uo[i][oo] = Q[b*NCH+i] * AU[((size_t)b*NCH+i)*DOUT + ob*8+oo];
  }
  __syncthreads();
  float p64 = P[b*65+NCH];
  float acc[2][8];
#pragma unroll
  for (int h=0;h<2;h++)
#pragma unroll
    for (int oo=0;oo<8;oo++) acc[h][oo]=0.f;
  int d0 = tid, d1 = tid+256;
  for (int i=0;i<64;i++){
    float k0 = KM[((size_t)b*NCH+i)*DIN + d0];
    float k1 = KM[((size_t)b*NCH+i)*DIN + d1];
#pragma unroll
    for (int oo=0;oo<8;oo++){
      float u = uo[i][oo];
      acc[0][oo] += u*k0;
      acc[1][oo] += u*k1;
    }
  }
#pragma unroll
  for (int oo=0;oo<8;oo++){
    int o = ob*8+oo;
    Mout[((size_t)b*DOUT + o)*DIN + d0] = p64*(M0[(size_t)o*DIN+d0] + acc[0][oo]);
    Mout[((size_t)b*DOUT + o)*DIN + d1] = p64*(M0[(size_t)o*DIN+d1] + acc[1][oo]);
  }
}

// ---------------- launch ----------------
extern "C" void kernel_launch(void* const* d_in, const int* in_sizes, int n_in,
                              void* d_out, int out_size, void* d_ws, size_t ws_size,
                              hipStream_t stream) {
  const float* x       = (const float*)d_in[0];
  const float* M0      = (const float*)d_in[1];
  const float* eta_w   = (const float*)d_in[2];
  const float* eta_b   = (const float*)d_in[3];
  const float* alpha_w = (const float*)d_in[4];
  const float* alpha_b = (const float*)d_in[5];
  const float* gate_w  = (const float*)d_in[6];
  const float* gate_b  = (const float*)d_in[7];
  float* out = (float*)d_out;

  float* ws = (float*)d_ws;
  // fp32 region
  float* KM   = ws;                    // 262144
  float* Dv   = KM   + 262144;
  float* G0   = Dv   + 262144;
  float* H0   = G0   + 262144;
  float* AU   = H0   + 262144;
  float* GT   = AU   + 262144;         // 32768 (transposed q-scaled KMD)
  float* WT   = GT   + 32768;          // 32768 (transposed q-scaled KMKM)
  float* C1   = WT   + 32768;          // 512
  float* C2   = C1   + 512;
  float* KM2  = C2   + 512;
  float* Q    = KM2  + 512;
  float* P    = Q    + 512;            // 1024 (8*65 used)
  float* DOTS = P    + 1024;           // 8192 (NB*8*64*2)
  // bf16 region
  unsigned short* M0h  = (unsigned short*)(DOTS + 8192);   // 262144 shorts
  unsigned short* KMh  = M0h  + 262144;                    // 262144
  unsigned short* Sh   = KMh  + 262144;                    // 2097152 (unused; kept for layout)
  unsigned short* UQTh = Sh   + 2097152;                   // 262144
  unsigned short* xh   = UQTh + 262144;                    // 16777216 (optional)

  size_t base_bytes = (size_t)((char*)xh - (char*)d_ws);
  size_t need_xh = base_bytes + (size_t)16777216*2;
  int use_xh = (ws_size >= need_xh) ? 1 : 0;
  unsigned short* xh_arg = use_xh ? xh : (unsigned short*)0;

  k0_m0h<<<dim3(256), 256, 0, stream>>>(M0, M0h);
  k1_stats<<<dim3(NCH, NB), 256, 0, stream>>>(x, eta_w, eta_b, alpha_w, alpha_b,
                                              gate_w, gate_b, KM, Dv, KMh, C1, C2, KM2, Q, xh_arg);
  k2_g0h0<<<dim3(NCH, NB, 2), 256, 0, stream>>>(KM, Dv, M0, G0, H0);
  k2b_gram<<<dim3(NCH, NB), 512, 0, stream>>>(KM, Dv, Q, GT, WT);
  k3a_rec<<<dim3(8, NB), 64, 0, stream>>>(G0, H0, GT, WT, Q, AU, UQTh, DOTS);
  k3b_chain<<<dim3(NB), 256, 0, stream>>>(M0, DOTS, C1, C2, KM2, P);
  k4_out<<<dim3(1024), 512, 0, stream>>>(x, xh, M0h, KMh, UQTh, P, out, use_xh);
  k5_mfin<<<dim3(64, NB), 256, 0, stream>>>(M0, KM, AU, P, Q, out + (size_t)NB*SEQ*DOUT);
}